// Round 13
// baseline (116.290 us; speedup 1.0000x reference)
//
#include <hip/hip_runtime.h>

#define NXROWS 32768
#define NY     4096
#define MCOLS  16
#define BLOCK  256
#define KSPLIT 8
#define KCHUNK (NY / KSPLIT)               // 512
#define NITER  (KCHUNK / 32)               // 16
#define ROWS_PER_BLOCK 256                 // 4 waves x 4 tiles x 16 rows
#define GRIDX  (NXROWS / ROWS_PER_BLOCK)   // 128 -> grid 128x8 = 1024 blocks

#define TPS_C 0.34657359027997264f  // 0.5*ln2: r^2 ln r = TPS_C * sq * log2(sq)

typedef __bf16 bf16x8 __attribute__((ext_vector_type(8)));
typedef short  s16x8  __attribute__((ext_vector_type(8)));
typedef float  f32x4  __attribute__((ext_vector_type(4)));
typedef unsigned int u32x4 __attribute__((ext_vector_type(4)));

// ws layout (bytes):
//   [0,      65536)   y8   : 4096 x 16B split-precision A-rows:
//                     {pk(-2yh0,-2yh1), pk(-2yh2,-2yl0), pk(-2yl1,-2yl2), pk(|y|2h,|y|2l)}
//   [65536, 196608)   cT   : bf16 [16][4096] = TPS_C * coeffs^T
//   [262144, +16MiB)  part : f32 [KSPLIT][NXROWS][MCOLS] (streamed; R9-proven footprint)
#define WS_Y8_OFF   0
#define WS_CT_OFF   65536
#define WS_PART_OFF 262144
#define WS_END      (WS_PART_OFF + (size_t)KSPLIT * NXROWS * MCOLS * 4)

static __device__ __forceinline__ unsigned short f2bfu(float f) {
    __bf16 h = (__bf16)f;
    return __builtin_bit_cast(unsigned short, h);
}
static __device__ __forceinline__ unsigned int pku(float a, float b) {
    return (unsigned int)f2bfu(a) | ((unsigned int)f2bfu(b) << 16);
}

// ---- prep: cT (TPS_C-scaled bf16 coeffs^T) + y8 split-precision table.
__global__ __launch_bounds__(BLOCK) void rbf_prep4(
    const float* __restrict__ y, const float* __restrict__ coeffs,
    u32x4* __restrict__ y8, unsigned int* __restrict__ cTw)
{
    const int idx = blockIdx.x * BLOCK + threadIdx.x;
    if (idx < MCOLS * NY / 2) {                   // cT build (u32-packed writes)
        const int m  = idx >> 11;
        const int jp = (idx & 2047) * 2;
        const unsigned short u0 = f2bfu(TPS_C * coeffs[(size_t)jp * MCOLS + m]);
        const unsigned short u1 = f2bfu(TPS_C * coeffs[(size_t)(jp + 1) * MCOLS + m]);
        cTw[((size_t)m * NY + jp) >> 1] = (unsigned int)u0 | ((unsigned int)u1 << 16);
    } else {                                      // y8 split-precision build
        const int j = idx - MCOLS * NY / 2;       // < NY
        const float y0 = y[3 * j], y1 = y[3 * j + 1], y2 = y[3 * j + 2];
        const float m0 = -2.f * y0, m1 = -2.f * y1, m2 = -2.f * y2;
        const float s  = y0 * y0 + y1 * y1 + y2 * y2;
        const float h0 = (float)(__bf16)m0, h1 = (float)(__bf16)m1, h2 = (float)(__bf16)m2;
        const float sh = (float)(__bf16)s;
        u32x4 v;
        v.x = pku(h0, h1);
        v.y = pku(h2, m0 - h0);
        v.z = pku(m1 - h1, m2 - h2);
        v.w = pku(s, s - sh);
        y8[j] = v;
    }
}

// ---- main: distance via split-precision MFMA (A=Y-tile, B=X-tile) + T12-style
// repack (cvt_pk + ds_bpermute) + accumulation MFMA.
// Frags (m89-verified): A lane l: row=l&15, k=(l>>4)*8+e; B: n=l&15, k=(l>>4)*8+e;
// C/D: col=l&15, row=(l>>4)*4+reg.
// Dist MFMA: D[j][i]: lane holds i=n (its x-row), j=4q+r  -> repack to A2
// (k=j) needs only cross-q exchange at fixed lanes n+16*((2q)&3), n+16*((2q+1)&3).
__global__ __launch_bounds__(BLOCK, 4) void rbf_mfma8(
    const float* __restrict__ x, const u32x4* __restrict__ y8,
    const unsigned short* __restrict__ cT, float* __restrict__ part)
{
    const int lane = threadIdx.x & 63;
    const int wid  = threadIdx.x >> 6;
    const int n    = lane & 15;
    const int q    = lane >> 4;
    const bool q0  = (q == 0), q1 = (q == 1), q01 = (q < 2);
    const int rowBase = blockIdx.x * ROWS_PER_BLOCK + wid * 64;
    const int kbase = blockIdx.y * KCHUNK;

    // --- one-time: B_x frags per t (split-precision x columns)
    s16x8 bx[4];
    #pragma unroll
    for (int t = 0; t < 4; ++t) {
        const int r = rowBase + t * 16 + n;
        const float x0 = x[r * 3], x1 = x[r * 3 + 1], x2 = x[r * 3 + 2];
        const float s  = x0 * x0 + x1 * x1 + x2 * x2;
        const float h0 = (float)(__bf16)x0, h1 = (float)(__bf16)x1, h2 = (float)(__bf16)x2;
        const float sh = (float)(__bf16)s;
        // q==0: k0-7  = [xh0,xh1,xh2, xh0,xh1,xh2, 1, 1]
        // q==1: k8-15 = [xl0,xl1,xl2, |x|2h, |x|2l, 0,0,0]
        const unsigned int a0 = pku(h0, h1), a1 = pku(h2, h0), a2 = pku(h1, h2);
        const unsigned int a3 = 0x3F803F80u;                       // (1,1)
        const unsigned int b0 = pku(x0 - h0, x1 - h1);
        const unsigned int b1 = pku(x2 - h2, s);
        const unsigned int b2 = pku(s - sh, 0.f);
        u32x4 w;
        w.x = q0 ? a0 : (q1 ? b0 : 0u);
        w.y = q0 ? a1 : (q1 ? b1 : 0u);
        w.z = q0 ? a2 : (q1 ? b2 : 0u);
        w.w = q0 ? a3 : 0u;
        bx[t] = __builtin_bit_cast(s16x8, w);
    }

    // bpermute source addrs (bytes): w0/w1 from n+16*((2q)&3); w2/w3 from n+16*((2q+1)&3)
    const int ad1 = 4 * (n + 16 * ((2 * q) & 3));
    const int ad2 = 4 * (n + 16 * ((2 * q + 1) & 3));

    const unsigned short* cb = cT + (size_t)n * NY + kbase + q * 8;

    f32x4 acc[4];
    #pragma unroll
    for (int t = 0; t < 4; ++t) acc[t] = (f32x4){0.f, 0.f, 0.f, 0.f};

    for (int ks = 0; ks < NITER; ++ks) {
        // loads: two y8 A-rows (16 distinct addrs each, L1 broadcast) + cT frag
        const u32x4 Ylo = y8[kbase + ks * 32 + n];
        const u32x4 Yhi = y8[kbase + ks * 32 + 16 + n];
        const s16x8 bc  = *reinterpret_cast<const s16x8*>(cb + ks * 32);

        // build A frags: q==0 holds k0-7 = y8 row; q==1 holds [-2yh(3), 1, 1, 0..]
        u32x4 wa, wb;
        wa.x = q01 ? Ylo.x : 0u;
        wa.y = q0 ? Ylo.y : (q1 ? ((Ylo.y & 0xFFFFu) | 0x3F800000u) : 0u);
        wa.z = q0 ? Ylo.z : (q1 ? 0x00003F80u : 0u);
        wa.w = q0 ? Ylo.w : 0u;
        wb.x = q01 ? Yhi.x : 0u;
        wb.y = q0 ? Yhi.y : (q1 ? ((Yhi.y & 0xFFFFu) | 0x3F800000u) : 0u);
        wb.z = q0 ? Yhi.z : (q1 ? 0x00003F80u : 0u);
        wb.w = q0 ? Yhi.w : 0u;
        const bf16x8 Alo = __builtin_bit_cast(bf16x8, wa);
        const bf16x8 Ahi = __builtin_bit_cast(bf16x8, wb);
        const bf16x8 bcf = __builtin_bit_cast(bf16x8, bc);

        #pragma unroll
        for (int t = 0; t < 4; ++t) {
            const bf16x8 bxt = __builtin_bit_cast(bf16x8, bx[t]);
            f32x4 Dlo = __builtin_amdgcn_mfma_f32_16x16x32_bf16(
                Alo, bxt, (f32x4){0.f, 0.f, 0.f, 0.f}, 0, 0, 0);
            f32x4 Dhi = __builtin_amdgcn_mfma_f32_16x16x32_bf16(
                Ahi, bxt, (f32x4){0.f, 0.f, 0.f, 0.f}, 0, 0, 0);
            float tl[4], th[4];
            #pragma unroll
            for (int r = 0; r < 4; ++r) {
                float sl = fmaxf(Dlo[r], 1e-14f);
                float sh = fmaxf(Dhi[r], 1e-14f);
                tl[r] = sl * __log2f(sl);
                th[r] = sh * __log2f(sh);
            }
            const int ul0 = (int)pku(tl[0], tl[1]);
            const int ul1 = (int)pku(tl[2], tl[3]);
            const int uh0 = (int)pku(th[0], th[1]);
            const int uh1 = (int)pku(th[2], th[3]);
            u32x4 wp;
            {
                const int l0 = __builtin_amdgcn_ds_bpermute(ad1, ul0);
                const int h0 = __builtin_amdgcn_ds_bpermute(ad1, uh0);
                const int l1 = __builtin_amdgcn_ds_bpermute(ad1, ul1);
                const int h1 = __builtin_amdgcn_ds_bpermute(ad1, uh1);
                const int l2 = __builtin_amdgcn_ds_bpermute(ad2, ul0);
                const int h2 = __builtin_amdgcn_ds_bpermute(ad2, uh0);
                const int l3 = __builtin_amdgcn_ds_bpermute(ad2, ul1);
                const int h3 = __builtin_amdgcn_ds_bpermute(ad2, uh1);
                wp.x = (unsigned int)(q01 ? l0 : h0);
                wp.y = (unsigned int)(q01 ? l1 : h1);
                wp.z = (unsigned int)(q01 ? l2 : h2);
                wp.w = (unsigned int)(q01 ? l3 : h3);
            }
            const bf16x8 A2 = __builtin_bit_cast(bf16x8, wp);
            acc[t] = __builtin_amdgcn_mfma_f32_16x16x32_bf16(A2, bcf, acc[t], 0, 0, 0);
        }
    }

    float* plane = part + (size_t)blockIdx.y * NXROWS * MCOLS;
    #pragma unroll
    for (int t = 0; t < 4; ++t) {
        float* o = plane + (size_t)(rowBase + t * 16 + q * 4) * MCOLS + n;
        #pragma unroll
        for (int r = 0; r < 4; ++r) o[(size_t)r * MCOLS] = acc[t][r];
    }
}

// ---- reduce KSPLIT f32 planes + polynomial tail; full overwrite of out.
__global__ __launch_bounds__(BLOCK) void rbf_reduce(
    const float* __restrict__ part, const float* __restrict__ x,
    const float* __restrict__ shift, const float* __restrict__ scale,
    const float* __restrict__ coeffs, const int* __restrict__ powers,
    int nR, float* __restrict__ out)
{
    const int idx = blockIdx.x * BLOCK + threadIdx.x;
    const int row = idx >> 2, mq = idx & 3;
    f32x4 s = {0.f, 0.f, 0.f, 0.f};
    #pragma unroll
    for (int sp = 0; sp < KSPLIT; ++sp) {
        const f32x4 v = *reinterpret_cast<const f32x4*>(
            part + (size_t)sp * NXROWS * MCOLS + (size_t)row * MCOLS + mq * 4);
        s += v;
    }
    float xh[3];
    #pragma unroll
    for (int d = 0; d < 3; ++d) xh[d] = (x[row * 3 + d] - shift[d]) / scale[d];
    for (int r = 0; r < nR; ++r) {
        float p = 1.0f;
        for (int d = 0; d < 3; ++d) {
            const int pw = powers[r * 3 + d];
            for (int k = 0; k < pw; ++k) p *= xh[d];
        }
        const f32x4 cv = *reinterpret_cast<const f32x4*>(
            coeffs + (size_t)(NY + r) * MCOLS + mq * 4);
        s += p * cv;
    }
    *reinterpret_cast<f32x4*>(out + (size_t)row * MCOLS + mq * 4) = s;
}

// ---- fallback (ws too small; effectively never): pure f32 atomic path.
__global__ __launch_bounds__(BLOCK) void rbf_f32_atomic(
    const float* __restrict__ x, const float* __restrict__ y,
    const float* __restrict__ coeffs, float* __restrict__ out)
{
    const int jbase = blockIdx.y * 512;
    const int row = blockIdx.x * BLOCK + threadIdx.x;
    const float x0 = x[row * 3], x1 = x[row * 3 + 1], x2 = x[row * 3 + 2];
    float acc[MCOLS];
    #pragma unroll
    for (int m = 0; m < MCOLS; ++m) acc[m] = 0.f;
    const float4* c4 = reinterpret_cast<const float4*>(coeffs) + (size_t)jbase * 4;
    for (int j = 0; j < 512; ++j) {
        const float dx = x0 - y[(jbase + j) * 3 + 0];
        const float dy = x1 - y[(jbase + j) * 3 + 1];
        const float dz = x2 - y[(jbase + j) * 3 + 2];
        const float sq = fmaxf(dx * dx + dy * dy + dz * dz, 1e-14f);
        const float t = TPS_C * sq * __log2f(sq);
        #pragma unroll
        for (int g = 0; g < 4; ++g) {
            const float4 cv = c4[j * 4 + g];
            acc[g * 4 + 0] += t * cv.x; acc[g * 4 + 1] += t * cv.y;
            acc[g * 4 + 2] += t * cv.z; acc[g * 4 + 3] += t * cv.w;
        }
    }
    #pragma unroll
    for (int m = 0; m < MCOLS; ++m)
        atomicAdd(&out[(size_t)row * MCOLS + m], acc[m]);
}

__global__ __launch_bounds__(BLOCK) void rbf_poly_atomic(
    const float* __restrict__ x, const float* __restrict__ shift,
    const float* __restrict__ scale, const float* __restrict__ coeffs,
    const int* __restrict__ powers, int nR, float* __restrict__ out)
{
    const int idx = blockIdx.x * BLOCK + threadIdx.x;
    const int row = idx >> 2, mq = idx & 3;
    float xh[3];
    #pragma unroll
    for (int d = 0; d < 3; ++d) xh[d] = (x[row * 3 + d] - shift[d]) / scale[d];
    f32x4 s = {0.f, 0.f, 0.f, 0.f};
    for (int r = 0; r < nR; ++r) {
        float p = 1.0f;
        for (int d = 0; d < 3; ++d) {
            const int pw = powers[r * 3 + d];
            for (int k = 0; k < pw; ++k) p *= xh[d];
        }
        const f32x4 cv = *reinterpret_cast<const f32x4*>(
            coeffs + (size_t)(NY + r) * MCOLS + mq * 4);
        s += p * cv;
    }
    float* o = out + (size_t)row * MCOLS + mq * 4;
    atomicAdd(o + 0, s.x); atomicAdd(o + 1, s.y);
    atomicAdd(o + 2, s.z); atomicAdd(o + 3, s.w);
}

extern "C" void kernel_launch(void* const* d_in, const int* in_sizes, int n_in,
                              void* d_out, int out_size, void* d_ws, size_t ws_size,
                              hipStream_t stream) {
    const float* x      = (const float*)d_in[0];
    const float* y      = (const float*)d_in[1];
    const float* shift  = (const float*)d_in[2];
    const float* scale  = (const float*)d_in[3];
    const float* coeffs = (const float*)d_in[4];
    const int*   powers = (const int*)d_in[5];
    const int    nR     = in_sizes[5] / 3;
    float* out = (float*)d_out;

    if (ws_size >= WS_END) {
        char* ws = (char*)d_ws;
        u32x4*          y8   = (u32x4*)(ws + WS_Y8_OFF);
        unsigned short* cT   = (unsigned short*)(ws + WS_CT_OFF);
        unsigned int*   cTw  = (unsigned int*)(ws + WS_CT_OFF);
        float*          part = (float*)(ws + WS_PART_OFF);
        rbf_prep4<<<(MCOLS * NY / 2 + NY) / BLOCK, BLOCK, 0, stream>>>(
            y, coeffs, y8, cTw);
        rbf_mfma8<<<dim3(GRIDX, KSPLIT), BLOCK, 0, stream>>>(x, y8, cT, part);
        rbf_reduce<<<NXROWS * 4 / BLOCK, BLOCK, 0, stream>>>(
            part, x, shift, scale, coeffs, powers, nR, out);
    } else {
        hipMemsetAsync(d_out, 0, (size_t)out_size * sizeof(float), stream);
        rbf_f32_atomic<<<dim3(NXROWS / BLOCK, NY / 512), BLOCK, 0, stream>>>(
            x, y, coeffs, out);
        rbf_poly_atomic<<<NXROWS * 4 / BLOCK, BLOCK, 0, stream>>>(
            x, shift, scale, coeffs, powers, nR, out);
    }
}

// Round 14
// 110.302 us; speedup vs baseline: 1.0543x; 1.0543x over previous
//
#include <hip/hip_runtime.h>

#define NXROWS 32768
#define NY     4096
#define MCOLS  16
#define BLOCK  256
#define KSPLIT 8
#define KCHUNK (NY / KSPLIT)               // 512
#define NITER  (KCHUNK / 32)               // 16
#define ROWS_PER_BLOCK 256                 // 4 waves x 4 tiles x 16 rows
#define GRIDX  (NXROWS / ROWS_PER_BLOCK)   // 128 -> grid 128x8 = 1024 blocks

#define TPS_C 0.34657359027997264f  // 0.5*ln2: r^2 ln r = TPS_C * sq * log2(sq)

typedef __bf16 bf16x8 __attribute__((ext_vector_type(8)));
typedef short  s16x8  __attribute__((ext_vector_type(8)));
typedef float  f32x4  __attribute__((ext_vector_type(4)));
typedef unsigned int u32x4 __attribute__((ext_vector_type(4)));

// ws layout (bytes):
//   [0,      65536)   y4   : 4096 x float4 (-2y0,-2y1,-2y2,|y|^2)
//   [65536, 196608)   cT   : bf16 [16][4096] = TPS_C * coeffs^T
//   [262144, +16MiB)  part : f32 [KSPLIT][NXROWS][MCOLS] (streamed; R9-proven
//                     2MB/XCD footprint -- R10 showed 4MB/XCD thrashes L2)
#define WS_Y4_OFF   0
#define WS_CT_OFF   65536
#define WS_PART_OFF 262144
#define WS_END      (WS_PART_OFF + (size_t)KSPLIT * NXROWS * MCOLS * 4)

static __device__ __forceinline__ unsigned short f2bfu(float f) {
    __bf16 h = (__bf16)f;
    return __builtin_bit_cast(unsigned short, h);
}

// native packed f32->bf16 (RNE). Guide T12 recipe: no builtin on gfx950;
// scalar casts may lower to a software RNE sequence (the phantom-inst suspect).
static __device__ __forceinline__ unsigned int cvtpk(float lo, float hi) {
    unsigned int r;
    asm("v_cvt_pk_bf16_f32 %0, %1, %2" : "=v"(r) : "v"(lo), "v"(hi));
    return r;
}

// ---- prep: cT (TPS_C-scaled bf16 coeffs^T) + pre-scaled y4.
__global__ __launch_bounds__(BLOCK) void rbf_prep3(
    const float* __restrict__ y, const float* __restrict__ coeffs,
    float4* __restrict__ y4, unsigned int* __restrict__ cTw)
{
    const int idx = blockIdx.x * BLOCK + threadIdx.x;
    if (idx < MCOLS * NY / 2) {                   // cT build (u32-packed writes)
        const int m  = idx >> 11;                 // 2048 j-pairs per m
        const int jp = (idx & 2047) * 2;
        const unsigned short u0 = f2bfu(TPS_C * coeffs[(size_t)jp * MCOLS + m]);
        const unsigned short u1 = f2bfu(TPS_C * coeffs[(size_t)(jp + 1) * MCOLS + m]);
        cTw[((size_t)m * NY + jp) >> 1] = (unsigned int)u0 | ((unsigned int)u1 << 16);
    } else {                                      // y4 build (pre-scaled)
        const int j = idx - MCOLS * NY / 2;       // < NY
        const float y0 = y[3 * j], y1 = y[3 * j + 1], y2 = y[3 * j + 2];
        y4[j] = make_float4(-2.f * y0, -2.f * y1, -2.f * y2,
                            y0 * y0 + y1 * y1 + y2 * y2);
    }
}

// ---- main: 4 waves x 4 M-tiles (64 rows/wave); K in 32-steps via MFMA.
// R9 structure; single change vs R11: af fragments built with paired
// v_cvt_pk_bf16_f32 (2 f32 -> packed 2xbf16, one inst) instead of 32
// scalar (__bf16) casts + vector inserts per K-step.
// A-frag: lane l -> row=l&15, k=(l>>4)*8+e ; B-frag: n=l&15, k=(l>>4)*8+e
// C/D:    lane l -> col=l&15, row=(l>>4)*4+reg   (m89-verified)
__global__ __launch_bounds__(BLOCK, 4) void rbf_mfma9(
    const float* __restrict__ x, const float4* __restrict__ y4,
    const unsigned short* __restrict__ cT, float* __restrict__ part)
{
    const int lane = threadIdx.x & 63;
    const int wid  = threadIdx.x >> 6;
    const int n    = lane & 15;
    const int q    = lane >> 4;
    const int rowBase = blockIdx.x * ROWS_PER_BLOCK + wid * 64;
    const int kbase = blockIdx.y * KCHUNK;

    float sx[4], a0[4], a1[4], a2[4];
    #pragma unroll
    for (int t = 0; t < 4; ++t) {
        const int r = rowBase + t * 16 + n;
        const float c0 = x[r * 3], c1 = x[r * 3 + 1], c2 = x[r * 3 + 2];
        sx[t] = c0 * c0 + c1 * c1 + c2 * c2;
        a0[t] = c0; a1[t] = c1; a2[t] = c2;   // y4 carries the -2 factor
    }

    const float4* yb = y4 + kbase + q * 8;
    const unsigned short* cb = cT + (size_t)n * NY + kbase + q * 8;

    f32x4 acc[4];
    #pragma unroll
    for (int t = 0; t < 4; ++t) acc[t] = (f32x4){0.f, 0.f, 0.f, 0.f};

    for (int ks = 0; ks < NITER; ++ks) {
        float4 yv[8];
        #pragma unroll
        for (int e = 0; e < 8; ++e) yv[e] = yb[ks * 32 + e];
        const s16x8 braw = *reinterpret_cast<const s16x8*>(cb + ks * 32);

        u32x4 w[4];
        #pragma unroll
        for (int e2 = 0; e2 < 4; ++e2) {
            const float4 va = yv[2 * e2];
            const float4 vb = yv[2 * e2 + 1];
            #pragma unroll
            for (int t = 0; t < 4; ++t) {
                float sa = fmaf(a0[t], va.x,
                           fmaf(a1[t], va.y,
                           fmaf(a2[t], va.z, sx[t] + va.w)));
                float sb = fmaf(a0[t], vb.x,
                           fmaf(a1[t], vb.y,
                           fmaf(a2[t], vb.z, sx[t] + vb.w)));
                sa = fmaxf(sa, 1e-14f);
                sb = fmaxf(sb, 1e-14f);
                w[t][e2] = cvtpk(sa * __log2f(sa), sb * __log2f(sb));
            }
        }
        const bf16x8 bf = __builtin_bit_cast(bf16x8, braw);
        #pragma unroll
        for (int t = 0; t < 4; ++t)
            acc[t] = __builtin_amdgcn_mfma_f32_16x16x32_bf16(
                __builtin_bit_cast(bf16x8, w[t]), bf, acc[t], 0, 0, 0);
    }

    float* plane = part + (size_t)blockIdx.y * NXROWS * MCOLS;
    #pragma unroll
    for (int t = 0; t < 4; ++t) {
        float* o = plane + (size_t)(rowBase + t * 16 + q * 4) * MCOLS + n;
        #pragma unroll
        for (int r = 0; r < 4; ++r) o[(size_t)r * MCOLS] = acc[t][r];
    }
}

// ---- reduce KSPLIT f32 planes + polynomial tail; full overwrite of out.
__global__ __launch_bounds__(BLOCK) void rbf_reduce(
    const float* __restrict__ part, const float* __restrict__ x,
    const float* __restrict__ shift, const float* __restrict__ scale,
    const float* __restrict__ coeffs, const int* __restrict__ powers,
    int nR, float* __restrict__ out)
{
    const int idx = blockIdx.x * BLOCK + threadIdx.x;
    const int row = idx >> 2, mq = idx & 3;
    f32x4 s = {0.f, 0.f, 0.f, 0.f};
    #pragma unroll
    for (int sp = 0; sp < KSPLIT; ++sp) {
        const f32x4 v = *reinterpret_cast<const f32x4*>(
            part + (size_t)sp * NXROWS * MCOLS + (size_t)row * MCOLS + mq * 4);
        s += v;
    }
    float xh[3];
    #pragma unroll
    for (int d = 0; d < 3; ++d) xh[d] = (x[row * 3 + d] - shift[d]) / scale[d];
    for (int r = 0; r < nR; ++r) {
        float p = 1.0f;
        for (int d = 0; d < 3; ++d) {
            const int pw = powers[r * 3 + d];
            for (int k = 0; k < pw; ++k) p *= xh[d];
        }
        const f32x4 cv = *reinterpret_cast<const f32x4*>(
            coeffs + (size_t)(NY + r) * MCOLS + mq * 4);
        s += p * cv;
    }
    *reinterpret_cast<f32x4*>(out + (size_t)row * MCOLS + mq * 4) = s;
}

// ---- fallback (ws too small; effectively never): pure f32 atomic path.
__global__ __launch_bounds__(BLOCK) void rbf_f32_atomic(
    const float* __restrict__ x, const float* __restrict__ y,
    const float* __restrict__ coeffs, float* __restrict__ out)
{
    const int jbase = blockIdx.y * 512;
    const int row = blockIdx.x * BLOCK + threadIdx.x;
    const float x0 = x[row * 3], x1 = x[row * 3 + 1], x2 = x[row * 3 + 2];
    float acc[MCOLS];
    #pragma unroll
    for (int m = 0; m < MCOLS; ++m) acc[m] = 0.f;
    const float4* c4 = reinterpret_cast<const float4*>(coeffs) + (size_t)jbase * 4;
    for (int j = 0; j < 512; ++j) {
        const float dx = x0 - y[(jbase + j) * 3 + 0];
        const float dy = x1 - y[(jbase + j) * 3 + 1];
        const float dz = x2 - y[(jbase + j) * 3 + 2];
        const float sq = fmaxf(dx * dx + dy * dy + dz * dz, 1e-14f);
        const float t = TPS_C * sq * __log2f(sq);
        #pragma unroll
        for (int g = 0; g < 4; ++g) {
            const float4 cv = c4[j * 4 + g];
            acc[g * 4 + 0] += t * cv.x; acc[g * 4 + 1] += t * cv.y;
            acc[g * 4 + 2] += t * cv.z; acc[g * 4 + 3] += t * cv.w;
        }
    }
    #pragma unroll
    for (int m = 0; m < MCOLS; ++m)
        atomicAdd(&out[(size_t)row * MCOLS + m], acc[m]);
}

__global__ __launch_bounds__(BLOCK) void rbf_poly_atomic(
    const float* __restrict__ x, const float* __restrict__ shift,
    const float* __restrict__ scale, const float* __restrict__ coeffs,
    const int* __restrict__ powers, int nR, float* __restrict__ out)
{
    const int idx = blockIdx.x * BLOCK + threadIdx.x;
    const int row = idx >> 2, mq = idx & 3;
    float xh[3];
    #pragma unroll
    for (int d = 0; d < 3; ++d) xh[d] = (x[row * 3 + d] - shift[d]) / scale[d];
    f32x4 s = {0.f, 0.f, 0.f, 0.f};
    for (int r = 0; r < nR; ++r) {
        float p = 1.0f;
        for (int d = 0; d < 3; ++d) {
            const int pw = powers[r * 3 + d];
            for (int k = 0; k < pw; ++k) p *= xh[d];
        }
        const f32x4 cv = *reinterpret_cast<const f32x4*>(
            coeffs + (size_t)(NY + r) * MCOLS + mq * 4);
        s += p * cv;
    }
    float* o = out + (size_t)row * MCOLS + mq * 4;
    atomicAdd(o + 0, s.x); atomicAdd(o + 1, s.y);
    atomicAdd(o + 2, s.z); atomicAdd(o + 3, s.w);
}

extern "C" void kernel_launch(void* const* d_in, const int* in_sizes, int n_in,
                              void* d_out, int out_size, void* d_ws, size_t ws_size,
                              hipStream_t stream) {
    const float* x      = (const float*)d_in[0];
    const float* y      = (const float*)d_in[1];
    const float* shift  = (const float*)d_in[2];
    const float* scale  = (const float*)d_in[3];
    const float* coeffs = (const float*)d_in[4];
    const int*   powers = (const int*)d_in[5];
    const int    nR     = in_sizes[5] / 3;
    float* out = (float*)d_out;

    if (ws_size >= WS_END) {
        char* ws = (char*)d_ws;
        float4*         y4   = (float4*)(ws + WS_Y4_OFF);
        unsigned short* cT   = (unsigned short*)(ws + WS_CT_OFF);
        unsigned int*   cTw  = (unsigned int*)(ws + WS_CT_OFF);
        float*          part = (float*)(ws + WS_PART_OFF);
        rbf_prep3<<<(MCOLS * NY / 2 + NY) / BLOCK, BLOCK, 0, stream>>>(
            y, coeffs, y4, cTw);
        rbf_mfma9<<<dim3(GRIDX, KSPLIT), BLOCK, 0, stream>>>(x, y4, cT, part);
        rbf_reduce<<<NXROWS * 4 / BLOCK, BLOCK, 0, stream>>>(
            part, x, shift, scale, coeffs, powers, nR, out);
    } else {
        hipMemsetAsync(d_out, 0, (size_t)out_size * sizeof(float), stream);
        rbf_f32_atomic<<<dim3(NXROWS / BLOCK, NY / 512), BLOCK, 0, stream>>>(
            x, y, coeffs, out);
        rbf_poly_atomic<<<NXROWS * 4 / BLOCK, BLOCK, 0, stream>>>(
            x, shift, scale, coeffs, powers, nR, out);
    }
}